// Round 14
// baseline (57.407 us; speedup 1.0000x reference)
//
#include <hip/hip_runtime.h>
#include <hip/hip_bf16.h>
#include <stdint.h>

#define BATCH 8
#define TSEQ 2048
#define DM 1024
#define NQKV 192

typedef short bf16x8 __attribute__((ext_vector_type(8)));
typedef short short4v __attribute__((ext_vector_type(4)));
typedef float f32x4 __attribute__((ext_vector_type(4)));

static __device__ __forceinline__ short f2bf(float f) {
    union { float f; uint32_t u; } v; v.f = f;
    uint32_t u = v.u;
    uint32_t r = (u + 0x7FFFu + ((u >> 16) & 1u)) >> 16;
    return (short)r;
}

static __device__ __forceinline__ f32x4 mfma16(bf16x8 a, bf16x8 b, f32x4 c) {
    return __builtin_amdgcn_mfma_f32_16x16x32_bf16(a, b, c, 0, 0, 0);
}

// Kernel 0: wt2[kchunk=0..127][n=0..191][8]. grid 128 x 192 threads.
__global__ __launch_bounds__(192) void prep_wt(const float* __restrict__ Wq,
                                               const float* __restrict__ Wk,
                                               const float* __restrict__ Wv,
                                               short* __restrict__ wt2) {
    int kc = blockIdx.x;
    int n = threadIdx.x;
    const float* src = (n < 64) ? Wq : (n < 128) ? Wk : Wv;
    int nn = n & 63;
    bf16x8 v;
    #pragma unroll
    for (int e = 0; e < 8; ++e)
        v[e] = f2bf(src[(kc * 8 + e) * 64 + nn]);
    *(bf16x8*)(wt2 + ((size_t)kc * 192 + n) * 8) = v;
}

// Kernel 1: QKV GEMM (R7 configuration, measured 15.1 us). Unchanged.
__global__ __launch_bounds__(256, 2) void qkv_gemm(const float* __restrict__ x,
                                                   const short* __restrict__ wt2,
                                                   short* __restrict__ qo,
                                                   short* __restrict__ kq,
                                                   short* __restrict__ vq) {
    __shared__ short Ab[2][32 * 32];
    __shared__ short Cs[32][192];
    int tid = threadIdx.x;
    int l = tid & 63, w = tid >> 6;
    int col = l & 15, g = l >> 4;
    int row0 = blockIdx.x * 32;

    int arow = tid >> 3, ap = tid & 7;
    const float* gA = x + (size_t)(row0 + arow) * DM + ap * 4;
    int awdst = arow * 32 + (((ap >> 1) ^ ((arow >> 1) & 3)) * 8) + (ap & 1) * 4;

    f32x4 acc[2][3];
    #pragma unroll
    for (int mf = 0; mf < 2; ++mf)
        #pragma unroll
        for (int nf = 0; nf < 3; ++nf) acc[mf][nf] = (f32x4){0.f, 0.f, 0.f, 0.f};

    float4 r0 = *(const float4*)(gA);
    float4 rcur = *(const float4*)(gA + 32);
    {
        short4v s = {f2bf(r0.x), f2bf(r0.y), f2bf(r0.z), f2bf(r0.w)};
        *(short4v*)&Ab[0][awdst] = s;
    }
    const short* bpw = wt2 + ((size_t)g * 192 + w * 48 + col) * 8;
    bf16x8 bcur[3], bnxt[3];
    #pragma unroll
    for (int nf = 0; nf < 3; ++nf)
        bcur[nf] = *(const bf16x8*)(bpw + (size_t)nf * 16 * 8);
    __syncthreads();

    int afr0, afr1;
    {
        int r0_ = col, r1_ = 16 + col;
        afr0 = r0_ * 32 + ((g ^ ((r0_ >> 1) & 3)) * 8);
        afr1 = r1_ * 32 + ((g ^ ((r1_ >> 1) & 3)) * 8);
    }

    for (int t = 0; t < 32; ++t) {
        float4 rn;
        if (t + 2 < 32) rn = *(const float4*)(gA + (t + 2) * 32);
        if (t + 1 < 32) {
            #pragma unroll
            for (int nf = 0; nf < 3; ++nf)
                bnxt[nf] = *(const bf16x8*)(bpw + ((size_t)(t + 1) * 4 * 192 + nf * 16) * 8);
            short4v s = {f2bf(rcur.x), f2bf(rcur.y), f2bf(rcur.z), f2bf(rcur.w)};
            *(short4v*)&Ab[(t + 1) & 1][awdst] = s;
        }
        bf16x8 a0 = *(const bf16x8*)&Ab[t & 1][afr0];
        bf16x8 a1 = *(const bf16x8*)&Ab[t & 1][afr1];
        #pragma unroll
        for (int nf = 0; nf < 3; ++nf) {
            acc[0][nf] = mfma16(a0, bcur[nf], acc[0][nf]);
            acc[1][nf] = mfma16(a1, bcur[nf], acc[1][nf]);
        }
        __syncthreads();
        rcur = rn;
        #pragma unroll
        for (int nf = 0; nf < 3; ++nf) bcur[nf] = bnxt[nf];
    }

    #pragma unroll
    for (int mf = 0; mf < 2; ++mf)
        #pragma unroll
        for (int nf = 0; nf < 3; ++nf) {
            int c = w * 48 + nf * 16 + col;
            #pragma unroll
            for (int j = 0; j < 4; ++j) {
                float sv = acc[mf][nf][j];
                if (c < 64) sv *= 0.03125f;
                Cs[mf * 16 + g * 4 + j][c] = f2bf(sv);
            }
        }
    __syncthreads();
    int b_ = row0 >> 11;
    int t0 = row0 & 2047;
    {
        int r = tid >> 3, c0 = (tid & 7) * 8;
        bf16x8 vv = *(const bf16x8*)&Cs[r][c0];
        *(bf16x8*)(qo + ((size_t)(b_ * TSEQ + t0 + r)) * 64 + c0) = vv;
    }
    {
        int chunk = tid >> 5, tl = tid & 31;
        bf16x8 vv = *(const bf16x8*)&Cs[tl][64 + chunk * 8];
        *(bf16x8*)(kq + ((size_t)(b_ * 8 + chunk) * TSEQ + t0 + tl) * 8) = vv;
    }
    {
        int tc = tid >> 6, d = tid & 63;
        bf16x8 vv;
        #pragma unroll
        for (int e = 0; e < 8; ++e) vv[e] = Cs[tc * 8 + e][128 + d];
        *(bf16x8*)(vq + (((size_t)b_ * 256 + (t0 >> 3) + tc) * 64 + d) * 8) = vv;
    }
}

// Kernel 2: causal flash attention, 32 q-rows/wave, uniform <=4-tile key chunks.
// grid 1024 x 256: gid = bid*4+w in [0,4096): b=gid>>9, qt=(gid&511)>>3 (32-row
// tile), ci=gid&7 (key chunk of 4). Jobs with ci >= nj exit immediately.
// Raw partial O (32x64 fp32) + psum written to slot gid; merge kernel divides.
__global__ __launch_bounds__(256) void attn(const short* __restrict__ qm,
                                            const short* __restrict__ kq,
                                            const short* __restrict__ vq,
                                            float* __restrict__ pob,
                                            float* __restrict__ pps) {
    __shared__ short Pb[4][32 * 64];   // 4 x 4 KB per-wave P transpose
    int tid = threadIdx.x;
    int l = tid & 63, w = tid >> 6;
    int col = l & 15, g = l >> 4;

    int gid = blockIdx.x * 4 + w;
    int b = gid >> 9;
    int qt = (gid & 511) >> 3;
    int ci = gid & 7;
    int nt = (qt >> 1) + 1;
    int nj = (nt + 3) >> 2;
    if (ci >= nj) return;
    int kt0 = ci * 4;
    int kt1 = min(nt, kt0 + 4);
    int lastkt = nt - 1;
    int q0 = qt * 32;

    // Q fragments: frag mf rows q0+mf*16, lane row col, k = g*8 (+32)
    bf16x8 qa[2][2];
    #pragma unroll
    for (int mf = 0; mf < 2; ++mf) {
        const short* qrow = qm + (size_t)(b * TSEQ + q0 + mf * 16 + col) * 64 + g * 8;
        qa[mf][0] = *(const bf16x8*)(qrow);
        qa[mf][1] = *(const bf16x8*)(qrow + 32);
    }

    const short* kb_ = kq + (size_t)(b * 8 + g) * TSEQ * 8;
    const short* kb4 = kq + (size_t)(b * 8 + 4 + g) * TSEQ * 8;
    const short* vb_ = vq + ((size_t)b * 256 + g) * 64 * 8;

    float psum[2][4];
    f32x4 o[2][4];
    #pragma unroll
    for (int mf = 0; mf < 2; ++mf)
        #pragma unroll
        for (int j = 0; j < 4; ++j) psum[mf][j] = 0.f;
    #pragma unroll
    for (int mf = 0; mf < 2; ++mf)
        #pragma unroll
        for (int df = 0; df < 4; ++df) o[mf][df] = (f32x4){0.f, 0.f, 0.f, 0.f};

    short* Pw = &Pb[w][0];

    bf16x8 kcur[8], knxt[8];
    {
        int key0 = kt0 * 64 + col;
        #pragma unroll
        for (int kf = 0; kf < 4; ++kf) {
            kcur[kf * 2]     = *(const bf16x8*)(kb_ + (size_t)(key0 + kf * 16) * 8);
            kcur[kf * 2 + 1] = *(const bf16x8*)(kb4 + (size_t)(key0 + kf * 16) * 8);
        }
    }

    for (int kt = kt0; kt < kt1; ++kt) {
        int k0 = kt * 64;
        // S = Q K^T (2 row-frags x 4 key-frags)
        f32x4 s[2][4];
        #pragma unroll
        for (int kf = 0; kf < 4; ++kf) {
            #pragma unroll
            for (int mf = 0; mf < 2; ++mf) {
                f32x4 a = (f32x4){0.f, 0.f, 0.f, 0.f};
                a = mfma16(qa[mf][0], kcur[kf * 2], a);
                a = mfma16(qa[mf][1], kcur[kf * 2 + 1], a);
                s[mf][kf] = a;
            }
        }
        // V fragments (current tile)
        bf16x8 vfr[8];
        const short* vt0 = vb_ + (size_t)(k0 >> 3) * 64 * 8;
        #pragma unroll
        for (int df = 0; df < 4; ++df) {
            int d = df * 16 + col;
            vfr[df * 2]     = *(const bf16x8*)(vt0 + (size_t)d * 8);
            vfr[df * 2 + 1] = *(const bf16x8*)(vt0 + (size_t)(256 + d) * 8);
        }
        // K prefetch (next tile)
        if (kt + 1 < kt1) {
            int key0 = (kt + 1) * 64 + col;
            #pragma unroll
            for (int kf = 0; kf < 4; ++kf) {
                knxt[kf * 2]     = *(const bf16x8*)(kb_ + (size_t)(key0 + kf * 16) * 8);
                knxt[kf * 2 + 1] = *(const bf16x8*)(kb4 + (size_t)(key0 + kf * 16) * 8);
            }
        }
        // mask (diagonal tile)
        if (kt == lastkt) {
            #pragma unroll
            for (int mf = 0; mf < 2; ++mf)
                #pragma unroll
                for (int kf = 0; kf < 4; ++kf) {
                    int key = k0 + kf * 16 + col;
                    int row = q0 + mf * 16 + g * 4;
                    #pragma unroll
                    for (int j = 0; j < 4; ++j)
                        if (key > row + j) s[mf][kf][j] = -1e30f;
                }
        }
        // p = exp(s), partial sums, pack transposed into per-wave LDS
        #pragma unroll
        for (int mf = 0; mf < 2; ++mf)
            #pragma unroll
            for (int kf = 0; kf < 4; ++kf)
                #pragma unroll
                for (int j = 0; j < 4; ++j) {
                    float pv = __expf(s[mf][kf][j]);
                    psum[mf][j] += pv;
                    int rr = mf * 16 + g * 4 + j;
                    int c = kf * 16 + col;
                    Pw[rr * 64 + ((((c >> 3) ^ (rr & 7)) << 3) | (c & 7))] = f2bf(pv);
                }
        bf16x8 pa[2][2];
        #pragma unroll
        for (int mf = 0; mf < 2; ++mf) {
            int prow = mf * 16 + col;
            #pragma unroll
            for (int ks = 0; ks < 2; ++ks) {
                int blk = ks * 4 + g;
                pa[mf][ks] = *(const bf16x8*)(Pw + prow * 64 + ((blk ^ (prow & 7)) << 3));
            }
        }
        // O += P V
        #pragma unroll
        for (int mf = 0; mf < 2; ++mf)
            #pragma unroll
            for (int df = 0; df < 4; ++df) {
                o[mf][df] = mfma16(pa[mf][0], vfr[df * 2], o[mf][df]);
                o[mf][df] = mfma16(pa[mf][1], vfr[df * 2 + 1], o[mf][df]);
            }
        #pragma unroll
        for (int i2 = 0; i2 < 8; ++i2) kcur[i2] = knxt[i2];
    }

    // row-sum reduce across the 16 col lanes
    #pragma unroll
    for (int off = 1; off <= 8; off <<= 1)
        #pragma unroll
        for (int mf = 0; mf < 2; ++mf)
            #pragma unroll
            for (int j = 0; j < 4; ++j)
                psum[mf][j] += __shfl_xor(psum[mf][j], off);

    // write partial slot gid
    #pragma unroll
    for (int mf = 0; mf < 2; ++mf)
        #pragma unroll
        for (int df = 0; df < 4; ++df)
            #pragma unroll
            for (int j = 0; j < 4; ++j)
                pob[(size_t)gid * 2048 + (mf * 16 + g * 4 + j) * 64 + df * 16 + col] = o[mf][df][j];
    if (col == 0)
        #pragma unroll
        for (int mf = 0; mf < 2; ++mf)
            #pragma unroll
            for (int j = 0; j < 4; ++j)
                pps[gid * 32 + mf * 16 + g * 4 + j] = psum[mf][j];
}

// Kernel 3: merge partials. grid 1024 x 256; 16 rows/block, 16 threads/row.
__global__ __launch_bounds__(256) void merge_out(const float* __restrict__ pob,
                                                 const float* __restrict__ pps,
                                                 float* __restrict__ out) {
    int tid = threadIdx.x;
    int r = tid >> 4;
    int dq = tid & 15;
    int qr = blockIdx.x * 16 + r;       // global row 0..16383
    int b = qr >> 11;
    int t = qr & 2047;
    int qt = t >> 5, r32 = t & 31;
    int nj = (((qt >> 1) + 1) + 3) >> 2;
    int slot0 = b * 512 + qt * 8;
    float4 acc = {0.f, 0.f, 0.f, 0.f};
    float ps = 0.f;
    for (int ci = 0; ci < nj; ++ci) {
        const float* pb = pob + ((size_t)(slot0 + ci) * 32 + r32) * 64 + dq * 4;
        float4 v = *(const float4*)pb;
        acc.x += v.x; acc.y += v.y; acc.z += v.z; acc.w += v.w;
        ps += pps[(slot0 + ci) * 32 + r32];
    }
    float inv = 1.f / ps;
    float4 res = {acc.x * inv, acc.y * inv, acc.z * inv, acc.w * inv};
    *(float4*)&out[(size_t)qr * 64 + dq * 4] = res;
}

extern "C" void kernel_launch(void* const* d_in, const int* in_sizes, int n_in,
                              void* d_out, int out_size, void* d_ws, size_t ws_size,
                              hipStream_t stream) {
    const float* x  = (const float*)d_in[0];
    const float* Wq = (const float*)d_in[1];
    const float* Wk = (const float*)d_in[2];
    const float* Wv = (const float*)d_in[3];
    float* out = (float*)d_out;

    char* ws = (char*)d_ws;
    short* wt2 = (short*)(ws);                        // 384 KB
    short* qb  = (short*)(ws + 0x60000);              // 2 MB
    short* kqb = (short*)(ws + 0x260000);             // 2 MB
    short* vqb = (short*)(ws + 0x460000);             // 2 MB
    float* pps = (float*)(ws + 0x660000);             // 4096*32*4 = 512 KB
    float* pob = (float*)(ws + 0x700000);             // 4096*2048*4 = 33.5 MB

    prep_wt<<<128, 192, 0, stream>>>(Wq, Wk, Wv, wt2);
    qkv_gemm<<<512, 256, 0, stream>>>(x, wt2, qb, kqb, vqb);
    attn<<<1024, 256, 0, stream>>>(qb, kqb, vqb, pob, pps);
    merge_out<<<1024, 256, 0, stream>>>(pob, pps, out);
}